// Round 3
// baseline (664.799 us; speedup 1.0000x reference)
//
#include <hip/hip_runtime.h>
#include <math.h>
#include <float.h>

#define HH 28
#define WW 28
#define NPIX 784
#define NMAXP 100
#define NSORT 1024
#define NTH 256
#define BIGR 0x3fffffff
// Essential-death sentinel: must stay FINITE after a bf16 round-trip.
// FLT_MAX rounds UP to +inf in bf16 (bf16 max finite = 3.3895e38) -> inf-inf=NaN
// in the harness diff. 1e30 is safely representable.
#define ESS_DEATH 1e30f

// One block per (sample, dim): blk = s*2 + which; which==0 -> H0 (8-conn, sublevel),
// which==1 -> H1 via superlevel on g=-x with virtual boundary node (4-conn + node 784).
__global__ __launch_bounds__(NTH)
void pd_kernel(const float* __restrict__ x, float* __restrict__ out)
{
    const int blk   = blockIdx.x;
    const int s     = blk >> 1;
    const int which = blk & 1;
    const int tid   = threadIdx.x;
    const int M     = NPIX + which;          // 784 (H0) or 785 (H1, incl. virtual node)

    __shared__ float vals[NPIX + 1];         // cell-space values (negated for H1)
    __shared__ float sk[NSORT];              // bitonic keys
    __shared__ int   si[NSORT];              // bitonic payload
    __shared__ float svals[NPIX + 1];        // rank-space (sorted) values
    __shared__ int   rankA[NPIX + 1];        // cell -> rank
    __shared__ int   orderA[NPIX + 1];       // rank -> cell
    __shared__ int   parent[NPIX + 1];       // UF over ranks
    __shared__ int   nbrR[(NPIX + 1) * 8];   // per-rank neighbor ranks (BIGR = none)
    __shared__ float pb[NSORT];              // pair births (output space)
    __shared__ float pdd[NSORT];             // pair deaths (output space)
    __shared__ int   npairs_s;

    // ---- load values (negate for superlevel H1); virtual node = -inf ----
    for (int i = tid; i < NPIX; i += NTH) {
        float v = x[s * NPIX + i];
        vals[i] = which ? -v : v;
    }
    if (tid == 0) vals[NPIX] = -INFINITY;
    __syncthreads();

    // ---- bitonic sort ascending by (value, cell idx) == stable argsort ----
    for (int i = tid; i < NSORT; i += NTH) {
        sk[i] = (i < M) ? vals[i] : INFINITY;
        si[i] = i;
    }
    for (int k = 2; k <= NSORT; k <<= 1)
        for (int j = k >> 1; j > 0; j >>= 1) {
            __syncthreads();
            for (int t = tid; t < NSORT; t += NTH) {
                int l = t ^ j;
                if (l > t) {
                    float av = sk[t], bv = sk[l];
                    int   ai = si[t], bi = si[l];
                    bool agtb = (av > bv) || (av == bv && ai > bi);
                    bool up = ((t & k) == 0);
                    if (agtb == up) { sk[t] = bv; si[t] = bi; sk[l] = av; si[l] = ai; }
                }
            }
        }
    __syncthreads();

    for (int r = tid; r < M; r += NTH) {
        int c = si[r];
        orderA[r] = c;
        rankA[c]  = r;
        svals[r]  = sk[r];
        parent[r] = r;
    }
    __syncthreads();

    // ---- phase B: per-rank neighbor ranks (parallel) ----
    for (int r = tid; r < M; r += NTH) {
        int c = orderA[r];
        int nr[8];
        #pragma unroll
        for (int k = 0; k < 8; ++k) nr[k] = BIGR;
        if (c < NPIX) {
            int ci = c / WW;
            int cj = c - ci * WW;
            if (which == 0) {
                const int di[8] = {-1,-1,-1, 0, 0, 1, 1, 1};
                const int dj[8] = {-1, 0, 1,-1, 1,-1, 0, 1};
                #pragma unroll
                for (int k = 0; k < 8; ++k) {
                    int ii = ci + di[k], jj = cj + dj[k];
                    if (ii >= 0 && ii < HH && jj >= 0 && jj < WW)
                        nr[k] = rankA[ii * WW + jj];
                }
            } else {
                const int di[4] = {-1, 1, 0, 0};
                const int dj[4] = { 0, 0,-1, 1};
                #pragma unroll
                for (int k = 0; k < 4; ++k) {
                    int ii = ci + di[k], jj = cj + dj[k];
                    if (ii >= 0 && ii < HH && jj >= 0 && jj < WW)
                        nr[k] = rankA[ii * WW + jj];
                }
                if (ci == 0 || ci == HH - 1 || cj == 0 || cj == WW - 1)
                    nr[4] = rankA[NPIX];
            }
        }
        #pragma unroll
        for (int k = 0; k < 8; ++k) nbrR[r * 8 + k] = nr[k];
    }
    __syncthreads();

    // ---- serial union-find in rank order (thread 0), rank space ----
    if (tid == 0) {
        int np = 0;
        for (int r = 0; r < M; ++r) {
            int nrk[8];
            #pragma unroll
            for (int k = 0; k < 8; ++k) nrk[k] = nbrR[r * 8 + k];  // 2x ds_read_b128
            float vc = svals[r];
            int   rc = r;                      // current root of r's component
            #pragma unroll
            for (int k = 0; k < 8; ++k) {
                int nr = nrk[k];
                if (nr >= r) continue;         // BIGR or not-yet-processed
                int root = nr;                 // find with path halving
                while (parent[root] != root) {
                    parent[root] = parent[parent[root]];
                    root = parent[root];
                }
                if (root == rc) continue;
                int y = root > rc ? root : rc; // younger = larger rank
                int e = root > rc ? rc : root; // elder  = smaller rank
                if (y != r) {                  // skip zero-persistence self pair
                    if (which == 0) { pb[np] = svals[y]; pdd[np] = vc; }
                    else            { pb[np] = -vc;      pdd[np] = -svals[y]; }
                    ++np;
                }
                parent[y] = e;
                rc = e;
            }
        }
        npairs_s = np;
    }
    __syncthreads();
    const int P = npairs_s;

    // ---- bitonic sort pairs by persistence descending (tie: lower idx first) ----
    for (int i = tid; i < NSORT; i += NTH) {
        sk[i] = (i < P) ? (pdd[i] - pb[i]) : -INFINITY;
        si[i] = i;
    }
    for (int k = 2; k <= NSORT; k <<= 1)
        for (int j = k >> 1; j > 0; j >>= 1) {
            __syncthreads();
            for (int t = tid; t < NSORT; t += NTH) {
                int l = t ^ j;
                if (l > t) {
                    float av = sk[t], bv = sk[l];
                    int   ai = si[t], bi = si[l];
                    bool aoutb = (av < bv) || (av == bv && ai > bi);  // descending
                    bool up = ((t & k) == 0);
                    if (aoutb == up) { sk[t] = bv; si[t] = bi; sk[l] = av; si[l] = ai; }
                }
            }
        }
    __syncthreads();

    // ---- write diagram: [32, 2, 100, 2] ----
    float* o = out + (size_t)(s * 2 + which) * NMAXP * 2;
    if (tid < NMAXP) {
        float b = 0.f, d = 0.f;
        if (which == 0) {
            if (tid == 0) { b = svals[0]; d = ESS_DEATH; }  // essential (min, "inf")
            else {
                int p = tid - 1;
                if (p < P) { int q = si[p]; b = pb[q]; d = pdd[q]; }
            }
        } else {
            if (tid < P) { int q = si[tid]; b = pb[q]; d = pdd[q]; }
        }
        o[tid * 2]     = b;
        o[tid * 2 + 1] = d;
    }
}

extern "C" void kernel_launch(void* const* d_in, const int* in_sizes, int n_in,
                              void* d_out, int out_size, void* d_ws, size_t ws_size,
                              hipStream_t stream) {
    (void)in_sizes; (void)n_in; (void)out_size; (void)d_ws; (void)ws_size;
    const float* x = (const float*)d_in[0];
    float* out = (float*)d_out;
    pd_kernel<<<dim3(64), dim3(NTH), 0, stream>>>(x, out);
}

// Round 4
// 230.145 us; speedup vs baseline: 2.8886x; 2.8886x over previous
//
#include <hip/hip_runtime.h>
#include <math.h>

#define HH 28
#define WW 28
#define NPIX 784
#define MMAX 785
#define NMAXP 100
#define NTH 512
#define ECAP 4096      // >= max possible edges: H0 8-conn undirected = 2970
#define PCAP 512       // >= max merges: basins-1 (H1 worst ~393)
#define SELCAP 512
// Essential-death sentinel: must stay FINITE after the harness's bf16
// round-trip (FLT_MAX rounds to +inf in bf16 -> inf-inf=NaN). 1e30 is safe.
#define ESS_DEATH 1e30f

// monotone float<->u32 (totally ordered as unsigned)
__device__ __forceinline__ unsigned f2mono(float f) {
    unsigned u = __float_as_uint(f);
    return (u & 0x80000000u) ? ~u : (u | 0x80000000u);
}
__device__ __forceinline__ float mono2f(unsigned m) {
    unsigned u = (m & 0x80000000u) ? (m ^ 0x80000000u) : ~m;
    return __uint_as_float(u);
}

// neighbors of cell c; returns count K, nb[k] = -1 if invalid.
// which==0: 8-conn. which==1: 4-conn + virtual boundary node NPIX.
__device__ __forceinline__ int get_nbrs(int c, int which, int* nb) {
    int ci = c / WW;
    int cj = c - ci * WW;
    if (which == 0) {
        const int di[8] = {-1,-1,-1, 0, 0, 1, 1, 1};
        const int dj[8] = {-1, 0, 1,-1, 1,-1, 0, 1};
        #pragma unroll
        for (int k = 0; k < 8; ++k) {
            int ii = ci + di[k], jj = cj + dj[k];
            nb[k] = (ii >= 0 && ii < HH && jj >= 0 && jj < WW) ? (ii * WW + jj) : -1;
        }
        return 8;
    } else {
        const int di[4] = {-1, 1, 0, 0};
        const int dj[4] = { 0, 0,-1, 1};
        #pragma unroll
        for (int k = 0; k < 4; ++k) {
            int ii = ci + di[k], jj = cj + dj[k];
            nb[k] = (ii >= 0 && ii < HH && jj >= 0 && jj < WW) ? (ii * WW + jj) : -1;
        }
        nb[4] = (ci == 0 || ci == HH - 1 || cj == 0 || cj == WW - 1) ? NPIX : -1;
        return 5;
    }
}

// One block per (sample, dim): blk = s*2 + which.
// which==0 -> H0 (8-conn sublevel on x); which==1 -> H1 via superlevel
// (sublevel on -x, 4-conn, virtual -inf boundary node).
__global__ __launch_bounds__(NTH)
void pd_kernel(const float* __restrict__ x, float* __restrict__ out)
{
    const int blk   = blockIdx.x;
    const int s     = blk >> 1;
    const int which = blk & 1;
    const int tid   = threadIdx.x;
    const int M     = NPIX + which;

    __shared__ float vals[MMAX];
    __shared__ int   dA[MMAX];              // steepest-descent / basin pointer
    __shared__ int   dB[MMAX];
    __shared__ int   parent[MMAX];          // UF over basin-root cells
    __shared__ unsigned long long ek[ECAP]; // sort1: (pairKey<<32)|wmono
    __shared__ unsigned long long e2[ECAP]; // sort2: (wmono<<20)|pairKey; reused for selection
    __shared__ float pb[PCAP], pdd[PCAP];   // recorded pairs (output space)
    __shared__ int   ecnt, scnt, npairs;
    __shared__ unsigned minmono;

    if (tid == 0) { ecnt = 0; scnt = 0; npairs = 0; minmono = 0xFFFFFFFFu; }

    // ---- load (negate for H1); track global min (H0 essential) ----
    unsigned lm = 0xFFFFFFFFu;
    for (int i = tid; i < NPIX; i += NTH) {
        float v = x[s * NPIX + i];
        float t = which ? -v : v;
        vals[i] = t;
        unsigned mv = f2mono(t);
        lm = lm < mv ? lm : mv;
    }
    if (tid == 0 && which) vals[NPIX] = -INFINITY;
    __syncthreads();
    atomicMin(&minmono, lm);

    // ---- steepest-descent pointer: lex-min (val, idx) over {self} U nbrs ----
    for (int i = tid; i < M; i += NTH) {
        int best = i; float bv = vals[i];
        if (i < NPIX) {
            int nb[8];
            int K = get_nbrs(i, which, nb);
            for (int k = 0; k < K; ++k) {
                int n = nb[k];
                if (n < 0) continue;
                float vn = vals[n];
                if (vn < bv || (vn == bv && n < best)) { bv = vn; best = n; }
            }
        }
        dA[i]     = best;   // == i iff local min (basin root)
        parent[i] = i;
    }
    __syncthreads();

    // ---- pointer jumping: 10 doublings cover depth <= 784 ----
    for (int rnd = 0; rnd < 5; ++rnd) {
        for (int i = tid; i < M; i += NTH) dB[i] = dA[dA[i]];
        __syncthreads();
        for (int i = tid; i < M; i += NTH) dA[i] = dB[dB[i]];
        __syncthreads();
    }
    // dA[i] = basin root cell of i

    // ---- emit cross-basin edges, directed from higher-key endpoint ----
    for (int c = tid; c < NPIX; c += NTH) {
        float vc = vals[c];
        int bc = dA[c];
        int nb[8];
        int K = get_nbrs(c, which, nb);
        for (int k = 0; k < K; ++k) {
            int n = nb[k];
            if (n < 0) continue;
            float vn = vals[n];
            bool lower = (vn < vc) || (vn == vc && n < c);
            if (!lower) continue;
            int bn = dA[n];
            if (bn == bc) continue;
            unsigned p0 = (unsigned)(bc < bn ? bc : bn);
            unsigned p1 = (unsigned)(bc < bn ? bn : bc);
            unsigned pk = (p0 << 10) | p1;          // basin ids <= 784 < 1024
            int idx = atomicAdd(&ecnt, 1);
            ek[idx] = ((unsigned long long)pk << 32) | (unsigned long long)f2mono(vc);
        }
    }
    __syncthreads();
    const int E = ecnt;

    // ---- sort1: group by pairKey, weight ascending within group ----
    int LEN = 1; while (LEN < E) LEN <<= 1;
    for (int i = E + tid; i < LEN; i += NTH) ek[i] = ~0ull;
    __syncthreads();
    for (int k = 2; k <= LEN; k <<= 1)
        for (int j = k >> 1; j > 0; j >>= 1) {
            for (int t = tid; t < LEN; t += NTH) {
                int l = t ^ j;
                if (l > t) {
                    unsigned long long a = ek[t], b = ek[l];
                    if ((a > b) == ((t & k) == 0)) { ek[t] = b; ek[l] = a; }
                }
            }
            __syncthreads();
        }

    // ---- dedup: keep min-weight edge per basin pair; repack (wmono<<20)|pairKey ----
    for (int i = tid; i < E; i += NTH) {
        unsigned long long cur = ek[i];
        bool surv = (i == 0) || ((cur >> 32) != (ek[i - 1] >> 32));
        if (surv) {
            int j = atomicAdd(&scnt, 1);
            e2[j] = ((cur & 0xFFFFFFFFull) << 20) | (cur >> 32);
        }
    }
    __syncthreads();
    const int S = scnt;

    // ---- sort2: surviving edges by weight ascending ----
    int LEN2 = 1; while (LEN2 < S) LEN2 <<= 1;
    for (int i = S + tid; i < LEN2; i += NTH) e2[i] = ~0ull;
    __syncthreads();
    for (int k = 2; k <= LEN2; k <<= 1)
        for (int j = k >> 1; j > 0; j >>= 1) {
            for (int t = tid; t < LEN2; t += NTH) {
                int l = t ^ j;
                if (l > t) {
                    unsigned long long a = e2[t], b = e2[l];
                    if ((a > b) == ((t & k) == 0)) { e2[t] = b; e2[l] = a; }
                }
            }
            __syncthreads();
        }

    // ---- serial Kruskal over ~S deduped edges (thread 0) ----
    if (tid == 0) {
        int np = 0;
        for (int i = 0; i < S; ++i) {
            unsigned long long kk = e2[i];
            unsigned pk = (unsigned)(kk & 0xFFFFFu);
            int ra = (int)(pk >> 10);
            int rb = (int)(pk & 1023u);
            while (parent[ra] != ra) { parent[ra] = parent[parent[ra]]; ra = parent[ra]; }
            while (parent[rb] != rb) { parent[rb] = parent[parent[rb]]; rb = parent[rb]; }
            if (ra == rb) continue;
            float va = vals[ra], vb = vals[rb];
            bool a_elder = (va < vb) || (va == vb && ra < rb);
            int e = a_elder ? ra : rb;
            int y = a_elder ? rb : ra;
            float w = mono2f((unsigned)(kk >> 20));
            if (which == 0) { pb[np] = vals[y]; pdd[np] = w; }
            else            { pb[np] = -w;      pdd[np] = -vals[y]; }
            ++np;
            parent[y] = e;
        }
        npairs = np;
    }
    __syncthreads();
    const int P = npairs;

    // ---- selection: top-NMAXP by persistence desc (reuse e2) ----
    for (int i = tid; i < SELCAP; i += NTH) {
        unsigned long long kk = ~0ull;
        if (i < P) {
            unsigned pm = __float_as_uint(pdd[i] - pb[i]);   // pers > 0 -> monotone
            kk = ((unsigned long long)(~pm) << 32) | (unsigned)i;
        }
        e2[i] = kk;
    }
    __syncthreads();
    for (int k = 2; k <= SELCAP; k <<= 1)
        for (int j = k >> 1; j > 0; j >>= 1) {
            for (int t = tid; t < SELCAP; t += NTH) {
                int l = t ^ j;
                if (l > t) {
                    unsigned long long a = e2[t], b = e2[l];
                    if ((a > b) == ((t & k) == 0)) { e2[t] = b; e2[l] = a; }
                }
            }
            __syncthreads();
        }

    // ---- write diagram: [32, 2, 100, 2] ----
    float* o = out + (size_t)blk * NMAXP * 2;
    if (tid < NMAXP) {
        float b = 0.f, d = 0.f;
        if (which == 0) {
            if (tid == 0) { b = mono2f(minmono); d = ESS_DEATH; }
            else {
                int p = tid - 1;
                if (p < P) { int q = (int)(e2[p] & 0xFFFFFFFFull); b = pb[q]; d = pdd[q]; }
            }
        } else {
            if (tid < P) { int q = (int)(e2[tid] & 0xFFFFFFFFull); b = pb[q]; d = pdd[q]; }
        }
        o[tid * 2]     = b;
        o[tid * 2 + 1] = d;
    }
}

extern "C" void kernel_launch(void* const* d_in, const int* in_sizes, int n_in,
                              void* d_out, int out_size, void* d_ws, size_t ws_size,
                              hipStream_t stream) {
    (void)in_sizes; (void)n_in; (void)out_size; (void)d_ws; (void)ws_size;
    const float* x = (const float*)d_in[0];
    float* out = (float*)d_out;
    pd_kernel<<<dim3(64), dim3(NTH), 0, stream>>>(x, out);
}

// Round 5
// 175.539 us; speedup vs baseline: 3.7872x; 1.3111x over previous
//
#include <hip/hip_runtime.h>
#include <math.h>

#define HH 28
#define WW 28
#define NPIX 784
#define MMAX 785
#define NMAXP 100
#define NTH 512
#define BCAP 512       // max basins (theory bound ~394)
#define HSZ 4096
#define HMASK 4095
#define ECAP 1024      // max deduped basin-pair edges (planar-ish: <= 3B ~ 1180 worst, ~470 actual)
#define PCAP 512
#define SELCAP 512
// Essential-death sentinel: must stay FINITE after the harness's bf16
// round-trip (FLT_MAX rounds to +inf in bf16 -> inf-inf=NaN). 1e30 is safe.
#define ESS_DEATH 1e30f

// monotone float<->u32 (totally ordered as unsigned)
__device__ __forceinline__ unsigned f2mono(float f) {
    unsigned u = __float_as_uint(f);
    return (u & 0x80000000u) ? ~u : (u | 0x80000000u);
}
__device__ __forceinline__ float mono2f(unsigned m) {
    unsigned u = (m & 0x80000000u) ? (m ^ 0x80000000u) : ~m;
    return __uint_as_float(u);
}

// neighbors of cell c; nb[k] = -1 if invalid.
// which==0: 8-conn. which==1: 4-conn + virtual boundary node NPIX.
__device__ __forceinline__ int get_nbrs(int c, int which, int* nb) {
    int ci = c / WW;
    int cj = c - ci * WW;
    if (which == 0) {
        const int di[8] = {-1,-1,-1, 0, 0, 1, 1, 1};
        const int dj[8] = {-1, 0, 1,-1, 1,-1, 0, 1};
        #pragma unroll
        for (int k = 0; k < 8; ++k) {
            int ii = ci + di[k], jj = cj + dj[k];
            nb[k] = (ii >= 0 && ii < HH && jj >= 0 && jj < WW) ? (ii * WW + jj) : -1;
        }
        return 8;
    } else {
        const int di[4] = {-1, 1, 0, 0};
        const int dj[4] = { 0, 0,-1, 1};
        #pragma unroll
        for (int k = 0; k < 4; ++k) {
            int ii = ci + di[k], jj = cj + dj[k];
            nb[k] = (ii >= 0 && ii < HH && jj >= 0 && jj < WW) ? (ii * WW + jj) : -1;
        }
        nb[4] = (ci == 0 || ci == HH - 1 || cj == 0 || cj == WW - 1) ? NPIX : -1;
        return 5;
    }
}

// One block per (sample, dim): blk = s*2 + which.
// which==0 -> H0 (8-conn sublevel on x); which==1 -> H1 via superlevel
// (sublevel on -x, 4-conn, virtual -inf boundary node).
__global__ __launch_bounds__(NTH)
void pd_kernel(const float* __restrict__ x, float* __restrict__ out)
{
    const int blk   = blockIdx.x;
    const int s     = blk >> 1;
    const int which = blk & 1;
    const int tid   = threadIdx.x;
    const int M     = NPIX + which;

    __shared__ float vals[MMAX];
    __shared__ int   dA[MMAX];                  // steepest-descent / basin root cell
    __shared__ int   dB[MMAX];                  // jump scratch, then cid at root cells
    __shared__ int   cido[MMAX];                // per-cell compact basin id
    __shared__ unsigned long long rootsSort[BCAP]; // (valmono<<32)|cell, sorted -> cid order
    __shared__ unsigned bval[BCAP];             // basin-min valmono per cid
    __shared__ int   parent[BCAP];              // UF over cids (elder = smaller cid)
    __shared__ unsigned hkey[HSZ];              // hash: pk+1 (0 = empty)
    __shared__ unsigned hval[HSZ];              // hash: min weight (monotone u32)
    __shared__ unsigned long long e2[ECAP];     // (wmono<<18)|pk ; reused for selection
    __shared__ float pb[PCAP], pdd[PCAP];       // recorded pairs (output space)
    __shared__ int   bcnt, scnt, npairs;

    if (tid == 0) { bcnt = 0; scnt = 0; npairs = 0; }
    for (int i = tid; i < HSZ; i += NTH) { hkey[i] = 0u; hval[i] = 0xFFFFFFFFu; }
    for (int i = tid; i < BCAP; i += NTH) { rootsSort[i] = ~0ull; parent[i] = i; }
    for (int i = tid; i < NPIX; i += NTH) {
        float v = x[s * NPIX + i];
        vals[i] = which ? -v : v;
    }
    if (tid == 0 && which) vals[NPIX] = -INFINITY;
    __syncthreads();

    // ---- steepest-descent pointer: lex-min (val, idx) over {self} U nbrs ----
    for (int i = tid; i < M; i += NTH) {
        int best = i; float bv = vals[i];
        if (i < NPIX) {
            int nb[8];
            int K = get_nbrs(i, which, nb);
            for (int k = 0; k < K; ++k) {
                int n = nb[k]; if (n < 0) continue;
                float vn = vals[n];
                if (vn < bv || (vn == bv && n < best)) { bv = vn; best = n; }
            }
        }
        dA[i] = best;   // == i iff local min (basin root)
    }
    __syncthreads();

    // ---- pointer jumping: 10 compositions -> 2^10 >= 784 ----
    for (int rnd = 0; rnd < 5; ++rnd) {
        for (int i = tid; i < M; i += NTH) dB[i] = dA[dA[i]];
        __syncthreads();
        for (int i = tid; i < M; i += NTH) dA[i] = dB[dB[i]];
        __syncthreads();
    }

    // ---- collect basin roots, sort by (valmono, cell) -> cid = value order ----
    for (int i = tid; i < M; i += NTH) {
        if (dA[i] == i) {
            int j = atomicAdd(&bcnt, 1);
            if (j < BCAP)
                rootsSort[j] = ((unsigned long long)f2mono(vals[i]) << 32) | (unsigned)i;
        }
    }
    __syncthreads();
    for (int k = 2; k <= BCAP; k <<= 1)
        for (int j = k >> 1; j > 0; j >>= 1) {
            for (int t = tid; t < BCAP; t += NTH) {
                int l = t ^ j;
                if (l > t) {
                    unsigned long long a = rootsSort[t], b = rootsSort[l];
                    if ((a > b) == ((t & k) == 0)) { rootsSort[t] = b; rootsSort[l] = a; }
                }
            }
            __syncthreads();
        }
    for (int b = tid; b < BCAP; b += NTH) {
        unsigned long long v = rootsSort[b];
        if (v != ~0ull) {
            int cell = (int)(v & 0xFFFFFFFFull);
            dB[cell] = b;                       // cid at root cell
            bval[b]  = (unsigned)(v >> 32);
        }
    }
    __syncthreads();
    for (int i = tid; i < M; i += NTH) cido[i] = dB[dA[i]];
    __syncthreads();

    // ---- cross-basin edges -> hash dedup (min weight per basin pair) ----
    for (int c = tid; c < NPIX; c += NTH) {
        float vc = vals[c];
        int bc = cido[c];
        int nb[8];
        int K = get_nbrs(c, which, nb);
        unsigned wm = f2mono(vc);
        for (int k = 0; k < K; ++k) {
            int n = nb[k]; if (n < 0) continue;
            float vn = vals[n];
            if (!(vn < vc || (vn == vc && n < c))) continue;  // emit from higher endpoint
            int bn = cido[n];
            if (bn == bc) continue;
            unsigned c0 = (unsigned)(bc < bn ? bc : bn);
            unsigned c1 = (unsigned)(bc < bn ? bn : bc);
            unsigned pk  = (c0 << 9) | c1;       // cids < 512 -> 18 bits
            unsigned key = pk + 1u;
            unsigned slot = (pk * 0x9E3779B1u) >> 20;  // 12-bit hash
            for (;;) {
                unsigned prev = atomicCAS(&hkey[slot], 0u, key);
                if (prev == 0u || prev == key) { atomicMin(&hval[slot], wm); break; }
                slot = (slot + 1) & HMASK;
            }
        }
    }
    __syncthreads();

    // ---- gather survivors ----
    for (int i = tid; i < HSZ; i += NTH) {
        unsigned key = hkey[i];
        if (key) {
            int j = atomicAdd(&scnt, 1);
            if (j < ECAP)
                e2[j] = ((unsigned long long)hval[i] << 18) | (unsigned long long)(key - 1u);
        }
    }
    __syncthreads();
    int S = scnt; if (S > ECAP) S = ECAP;

    // ---- sort by (weight, pk) ascending ----
    int LEN = 1; while (LEN < S) LEN <<= 1;
    for (int i = S + tid; i < LEN; i += NTH) e2[i] = ~0ull;
    __syncthreads();
    for (int k = 2; k <= LEN; k <<= 1)
        for (int j = k >> 1; j > 0; j >>= 1) {
            for (int t = tid; t < LEN; t += NTH) {
                int l = t ^ j;
                if (l > t) {
                    unsigned long long a = e2[t], b = e2[l];
                    if ((a > b) == ((t & k) == 0)) { e2[t] = b; e2[l] = a; }
                }
            }
            __syncthreads();
        }

    // ---- serial Kruskal over deduped sorted edges (thread 0) ----
    // elder = smaller cid (cids are value-ordered); paired find chains overlap
    // their LDS latencies; next edge prefetched.
    if (tid == 0) {
        int np = 0;
        unsigned long long kk = (S > 0) ? e2[0] : 0ull;
        for (int i = 0; i < S; ++i) {
            int nx = i + 1; if (nx >= ECAP) nx = ECAP - 1;
            unsigned long long kn = e2[nx];          // prefetch next edge
            unsigned pk = (unsigned)(kk & 0x3FFFFull);
            int ra = (int)(pk >> 9), rb = (int)(pk & 511u);
            for (;;) {
                int qa = parent[ra];                 // paired loads overlap
                int qb = parent[rb];
                if (qa == ra && qb == rb) break;
                int ga = parent[qa];
                int gb = parent[qb];
                parent[ra] = ga; parent[rb] = gb;    // path splitting
                ra = ga; rb = gb;
            }
            if (ra != rb) {
                int e = ra < rb ? ra : rb;
                int y = ra ^ rb ^ e;
                parent[y] = e;
                float bf = mono2f(bval[y]);
                float w  = mono2f((unsigned)(kk >> 18));
                if (which == 0) { pb[np] = bf; pdd[np] = w; }
                else            { pb[np] = -w; pdd[np] = -bf; }
                ++np;
            }
            kk = kn;
        }
        npairs = np;
    }
    __syncthreads();
    const int P = npairs;

    // ---- selection: top-NMAXP by persistence desc (reuse e2) ----
    for (int i = tid; i < SELCAP; i += NTH) {
        unsigned long long kk2 = ~0ull;
        if (i < P) {
            unsigned pm = __float_as_uint(pdd[i] - pb[i]);  // pers > 0 -> monotone
            kk2 = ((unsigned long long)(~pm) << 32) | (unsigned)i;
        }
        e2[i] = kk2;
    }
    __syncthreads();
    for (int k = 2; k <= SELCAP; k <<= 1)
        for (int j = k >> 1; j > 0; j >>= 1) {
            for (int t = tid; t < SELCAP; t += NTH) {
                int l = t ^ j;
                if (l > t) {
                    unsigned long long a = e2[t], b = e2[l];
                    if ((a > b) == ((t & k) == 0)) { e2[t] = b; e2[l] = a; }
                }
            }
            __syncthreads();
        }

    // ---- write diagram: [32, 2, 100, 2] ----
    float* o = out + (size_t)blk * NMAXP * 2;
    if (tid < NMAXP) {
        float b = 0.f, d = 0.f;
        if (which == 0) {
            if (tid == 0) { b = mono2f(bval[0]); d = ESS_DEATH; }  // essential (min, "inf")
            else {
                int p = tid - 1;
                if (p < P) { int q = (int)(e2[p] & 0xFFFFFFFFull); b = pb[q]; d = pdd[q]; }
            }
        } else {
            if (tid < P) { int q = (int)(e2[tid] & 0xFFFFFFFFull); b = pb[q]; d = pdd[q]; }
        }
        o[tid * 2]     = b;
        o[tid * 2 + 1] = d;
    }
}

extern "C" void kernel_launch(void* const* d_in, const int* in_sizes, int n_in,
                              void* d_out, int out_size, void* d_ws, size_t ws_size,
                              hipStream_t stream) {
    (void)in_sizes; (void)n_in; (void)out_size; (void)d_ws; (void)ws_size;
    const float* x = (const float*)d_in[0];
    float* out = (float*)d_out;
    pd_kernel<<<dim3(64), dim3(NTH), 0, stream>>>(x, out);
}